// Round 1
// baseline (5441.084 us; speedup 1.0000x reference)
//
#include <hip/hip_runtime.h>

#define T_SZ 65536
#define K_SZ 2048
#define D_SZ 256

// numpy pairwise_sum replica for 128 contiguous squared elements.
// numpy: r[0..7] = a[0..7]; for i=8..120 step 8: r[j]+=a[i+j];
//        res = ((r0+r1)+(r2+r3))+((r4+r5)+(r6+r7))
// applied to a[i]^2 with each square rounded BEFORE the add (contract off).
__device__ __forceinline__ float pairwise128_sq(const float* __restrict__ a) {
#pragma clang fp contract(off)
  float r0 = a[0] * a[0], r1 = a[1] * a[1], r2 = a[2] * a[2], r3 = a[3] * a[3];
  float r4 = a[4] * a[4], r5 = a[5] * a[5], r6 = a[6] * a[6], r7 = a[7] * a[7];
#pragma unroll
  for (int i = 8; i < 128; i += 8) {
    r0 += a[i + 0] * a[i + 0];
    r1 += a[i + 1] * a[i + 1];
    r2 += a[i + 2] * a[i + 2];
    r3 += a[i + 3] * a[i + 3];
    r4 += a[i + 4] * a[i + 4];
    r5 += a[i + 5] * a[i + 5];
    r6 += a[i + 6] * a[i + 6];
    r7 += a[i + 7] * a[i + 7];
  }
  return ((r0 + r1) + (r2 + r3)) + ((r4 + r5) + (r6 + r7));
}

// e_sq[k] = numpy-pairwise sum of e[k][:]^2  (n=256 -> 128+128 split)
__global__ void esq_kernel(const float* __restrict__ e, float* __restrict__ esq) {
  int k = blockIdx.x * 64 + threadIdx.x;  // 32 blocks x 64 = 2048
  const float* er = e + (size_t)k * D_SZ;
  esq[k] = pairwise128_sq(er) + pairwise128_sq(er + 128);
}

// Main kernel: per block 128 rows x all 2048 codes.
// threads: tx = tid&15 (code dim, 8 codes each), ty = tid>>4 (row dim, 8 rows each)
__global__ __launch_bounds__(256, 2) void vq_argmin_kernel(
    const float* __restrict__ x, const float* __restrict__ e,
    const float* __restrict__ esq_g, float* __restrict__ outIdx) {
  // xs: d-major x slice [buf][d(16)][row 128 + pad4]  (pitch 132 -> rows 8*ty map to banks 8ty%32, conflict-free)
  // es: d-major e slice [buf][d(16)][code-slot 128]; slot layout: h-half major then tx so
  //     dwords 4tx..4tx+3 hold codes 8tx..8tx+3 (h=0) and 64+4tx holds 8tx+4..7 (h=1): 2-way only.
  __shared__ __align__(16) float xs[2][16][132];
  __shared__ __align__(16) float es[2][16][128];
  __shared__ float xsq_s[128];

  const int tid = threadIdx.x;
  const int tx = tid & 15;
  const int ty = tid >> 4;
  const int rowbase = blockIdx.x * 128;

  // --- x_sq for the block's 128 rows, numpy pairwise (threads 0..127, once) ---
  if (tid < 128) {
    const float* xr = x + (size_t)(rowbase + tid) * D_SZ;
    xsq_s[tid] = pairwise128_sq(xr) + pairwise128_sq(xr + 128);
  }

  const float4* x4 = reinterpret_cast<const float4*>(x);
  const float4* e4 = reinterpret_cast<const float4*>(e);

  float4 px0, px1, pe0, pe1;  // prefetch registers

  auto prefetch = [&](int round) {
    const int chunk = round >> 4, dstep = round & 15;
    {
      int row = tid >> 2, q = tid & 3;
      px0 = x4[(size_t)(rowbase + row) * 64 + dstep * 4 + q];
      px1 = x4[(size_t)(rowbase + 64 + row) * 64 + dstep * 4 + q];
    }
    {
      int code0 = tid >> 2, q = tid & 3;
      pe0 = e4[(size_t)(chunk * 128 + code0) * 64 + dstep * 4 + q];
      pe1 = e4[(size_t)(chunk * 128 + 64 + code0) * 64 + dstep * 4 + q];
    }
  };

  auto write_lds = [&](int buf) {
    int row = tid >> 2, q = tid & 3;
    xs[buf][4 * q + 0][row] = px0.x;
    xs[buf][4 * q + 1][row] = px0.y;
    xs[buf][4 * q + 2][row] = px0.z;
    xs[buf][4 * q + 3][row] = px0.w;
    xs[buf][4 * q + 0][64 + row] = px1.x;
    xs[buf][4 * q + 1][64 + row] = px1.y;
    xs[buf][4 * q + 2][64 + row] = px1.z;
    xs[buf][4 * q + 3][64 + row] = px1.w;
    int code = tid >> 2;  // 0..63 (pe0), +64 (pe1)
    int slot0 = ((code >> 2) & 1) * 64 + (code >> 3) * 4 + (code & 3);
    es[buf][4 * q + 0][slot0] = pe0.x;
    es[buf][4 * q + 1][slot0] = pe0.y;
    es[buf][4 * q + 2][slot0] = pe0.z;
    es[buf][4 * q + 3][slot0] = pe0.w;
    int code1 = 64 + code;
    int slot1 = ((code1 >> 2) & 1) * 64 + (code1 >> 3) * 4 + (code1 & 3);
    es[buf][4 * q + 0][slot1] = pe1.x;
    es[buf][4 * q + 1][slot1] = pe1.y;
    es[buf][4 * q + 2][slot1] = pe1.z;
    es[buf][4 * q + 3][slot1] = pe1.w;
  };

  prefetch(0);
  write_lds(0);
  __syncthreads();

  float xsq[8];
#pragma unroll
  for (int r = 0; r < 8; ++r) xsq[r] = xsq_s[8 * ty + r];

  float acc[8][8];
#pragma unroll
  for (int r = 0; r < 8; ++r)
#pragma unroll
    for (int c = 0; c < 8; ++c) acc[r][c] = 0.0f;

  float bestv[8];
  int besti[8];
#pragma unroll
  for (int r = 0; r < 8; ++r) {
    bestv[r] = 3.402823466e38f;
    besti[r] = 0;
  }

#pragma unroll 1
  for (int chunk = 0; chunk < 16; ++chunk) {
#pragma unroll 1
    for (int dstep = 0; dstep < 16; ++dstep) {
      const int round = chunk * 16 + dstep;
      const int buf = round & 1;
      if (round < 255) prefetch(round + 1);
#pragma unroll
      for (int d = 0; d < 16; ++d) {
        float4 xv0 = *reinterpret_cast<const float4*>(&xs[buf][d][8 * ty]);
        float4 xv1 = *reinterpret_cast<const float4*>(&xs[buf][d][8 * ty + 4]);
        float4 ev0 = *reinterpret_cast<const float4*>(&es[buf][d][4 * tx]);
        float4 ev1 = *reinterpret_cast<const float4*>(&es[buf][d][64 + 4 * tx]);
        float xr_[8] = {xv0.x, xv0.y, xv0.z, xv0.w, xv1.x, xv1.y, xv1.z, xv1.w};
        float ec_[8] = {ev0.x, ev0.y, ev0.z, ev0.w, ev1.x, ev1.y, ev1.z, ev1.w};
#pragma unroll
        for (int r = 0; r < 8; ++r)
#pragma unroll
          for (int c = 0; c < 8; ++c)
            acc[r][c] = __builtin_fmaf(xr_[r], ec_[c], acc[r][c]);
      }
      if (round < 255) write_lds(buf ^ 1);
      __syncthreads();
    }
    // epilogue for this 128-code chunk: dist = (x_sq - 2*cross) + e_sq, running argmin
    const int nbase = chunk * 128;
#pragma unroll
    for (int c = 0; c < 8; ++c) {
      const int k = nbase + 8 * tx + c;  // ascending k within thread
      const float esq = esq_g[k];
#pragma unroll
      for (int r = 0; r < 8; ++r) {
        float t1 = xsq[r] - 2.0f * acc[r][c];  // 2*acc exact; sub matches np
        float dist = t1 + esq;
        bool better = dist < bestv[r];  // strict <: first (lowest k) wins ties
        bestv[r] = better ? dist : bestv[r];
        besti[r] = better ? k : besti[r];
        acc[r][c] = 0.0f;
      }
    }
  }

  // fold the 16 tx-lanes per row (lane bits 0..3 = tx); tie-break: lowest index
#pragma unroll
  for (int m = 1; m < 16; m <<= 1) {
#pragma unroll
    for (int r = 0; r < 8; ++r) {
      float ov = __shfl_xor(bestv[r], m, 64);
      int oi = __shfl_xor(besti[r], m, 64);
      bool take = (ov < bestv[r]) || ((ov == bestv[r]) && (oi < besti[r]));
      bestv[r] = take ? ov : bestv[r];
      besti[r] = take ? oi : besti[r];
    }
  }
  if (tx == 0) {
#pragma unroll
    for (int r = 0; r < 8; ++r)
      outIdx[rowbase + 8 * ty + r] = (float)besti[r];
  }
}

// out0 = x + (e[idx] - x), elementwise fp32 exactly as the reference
__global__ __launch_bounds__(256) void decode_kernel(
    const float* __restrict__ x, const float* __restrict__ e,
    const float* __restrict__ idxf, float* __restrict__ out) {
  size_t g = (size_t)blockIdx.x * 256 + threadIdx.x;  // float4 index
  size_t t = g >> 6;
  int q = (int)(g & 63);
  int idx = (int)idxf[t];  // wave-uniform
  const float4* x4 = reinterpret_cast<const float4*>(x);
  const float4* e4 = reinterpret_cast<const float4*>(e);
  float4 xv = x4[t * 64 + q];
  float4 qv = e4[(size_t)idx * 64 + q];
  float4 o;
  o.x = xv.x + (qv.x - xv.x);
  o.y = xv.y + (qv.y - xv.y);
  o.z = xv.z + (qv.z - xv.z);
  o.w = xv.w + (qv.w - xv.w);
  reinterpret_cast<float4*>(out)[g] = o;
}

extern "C" void kernel_launch(void* const* d_in, const int* in_sizes, int n_in,
                              void* d_out, int out_size, void* d_ws, size_t ws_size,
                              hipStream_t stream) {
  const float* x = (const float*)d_in[0];      // (65536, 256) fp32
  const float* e = (const float*)d_in[1];      // (2048, 256) fp32
  float* out = (float*)d_out;                  // [T*D quantized | T indices-as-float]
  float* esq = (float*)d_ws;                   // 2048 floats scratch
  float* outIdx = out + (size_t)T_SZ * D_SZ;

  esq_kernel<<<K_SZ / 64, 64, 0, stream>>>(e, esq);
  vq_argmin_kernel<<<T_SZ / 128, 256, 0, stream>>>(x, e, esq, outIdx);
  decode_kernel<<<(T_SZ * (D_SZ / 4)) / 256, 256, 0, stream>>>(x, e, outIdx, out);
}